// Round 8
// baseline (277.867 us; speedup 1.0000x reference)
//
#include <hip/hip_runtime.h>

// GraphAttention: B=4, N=2048, F=256, H=8, F_=64; out [B, N, 512].
// 4 dispatches: k_mask (A->bitmask, init maxn) -> k_gemm1 (h=X@W, inline
// fp32->bf16 conv) -> k_att (att_s/att_n + per-bh max(att_n) atomic) ->
// k_attn_av (fused masked softmax @ h; per-row upper-bound max c_i =
// leaky(s_i+maxn) -- no max pass, no online rescale; l via ones-MFMA).
// Input dtype detected from A word 0: self-loop A[0][0]=1 => fp32 word0
// is exactly 1.0f; under bf16 the low half is 0x3f80 => word != 0/1.

constexpr int GN  = 2048;
constexpr int GFI = 256;
constexpr int GHF = 512;

using sh8    = __attribute__((ext_vector_type(8))) short;          // 8 bf16
using us4g   = __attribute__((ext_vector_type(4))) unsigned short;
using f32x4g = __attribute__((ext_vector_type(4))) float;
using i32x4g = __attribute__((ext_vector_type(4))) int;

__device__ inline float gat_bf2f(unsigned short u) {
    union { unsigned int i; float f; } c; c.i = ((unsigned int)u) << 16; return c.f;
}
__device__ inline unsigned short gat_f2bf(float f) {
    union { float f; unsigned int i; } c; c.f = f;
    return (unsigned short)((c.i + 0x7fffu + ((c.i >> 16) & 1u)) >> 16); // RNE
}
__device__ inline int gat_isf32(const float* __restrict__ Aw) {
    float a = Aw[0];                       // wave-uniform broadcast load
    return (a == 0.0f) || (a == 1.0f);     // deterministic via self-loop
}
// order-preserving float<->uint encode for atomicMax
__device__ inline unsigned int gat_enc(float f) {
    union { float f; unsigned int u; } c; c.f = f;
    return (c.u & 0x80000000u) ? ~c.u : (c.u | 0x80000000u);
}
__device__ inline float gat_dec(unsigned int e) {
    union { float f; unsigned int u; } c;
    c.u = (e & 0x80000000u) ? (e & 0x7fffffffu) : ~e;
    return c.f;
}

__global__ void GraphAttention_62981400429165_kernel() {}

// --------------------------------------------------------------------------
// k_mask: A -> bitmask (1 bit per entry). Also inits maxn_enc (block 0).
// grid 65536 x 256, one coalesced HBM pass.
// --------------------------------------------------------------------------
__global__ __launch_bounds__(256) void k_mask(const void* __restrict__ Araw,
                                              unsigned long long* __restrict__ mask,
                                              unsigned int* __restrict__ maxn_enc) {
    if (blockIdx.x == 0 && threadIdx.x < 32) maxn_enc[threadIdx.x] = 0u;
    int isf = gat_isf32((const float*)Araw);
    size_t idx = (size_t)blockIdx.x * 256 + threadIdx.x;
    int nz;
    if (isf) nz = (((const float*)Araw)[idx] != 0.0f);
    else     nz = (((const unsigned short*)Araw)[idx] != 0);
    unsigned long long bal = __ballot(nz);
    if ((threadIdx.x & 63) == 0) mask[idx >> 6] = bal;
}

// --------------------------------------------------------------------------
// k_gemm1: h = X @ W per (b,h), inline fp32->bf16 conversion.
// M=2048,K=256,Ncol=64. h_t[(bh*64+o)*2048+n] bf16. grid 256 (bh*8+it) x 256.
// --------------------------------------------------------------------------
constexpr int LDW = 264;
__global__ __launch_bounds__(256) void k_gemm1(const void* __restrict__ Xraw,
                                               const void* __restrict__ Wraw,
                                               const float* __restrict__ Aw,
                                               unsigned short* __restrict__ h_t) {
    int blk = blockIdx.x;
    int bh = blk >> 3, it = blk & 7;
    int b = bh >> 3, hh = bh & 7;
    int isf = gat_isf32(Aw);
    __shared__ unsigned short Wt[64 * LDW];
    for (int idx = threadIdx.x; idx < 256 * 64; idx += 256) {
        int k = idx >> 6, col = idx & 63;
        unsigned short wv;
        if (isf) wv = gat_f2bf(((const float*)Wraw)[(hh * 256 + k) * 64 + col]);
        else     wv = ((const unsigned short*)Wraw)[(hh * 256 + k) * 64 + col];
        Wt[col * LDW + k] = wv;
    }
    __syncthreads();
#if defined(__gfx950__)
    int wave = threadIdx.x >> 6, lane = threadIdx.x & 63;
    int lrw = lane & 15, quad = lane >> 4;
    int row0 = it * 256 + wave * 64;
    f32x4g acc[4][4] = {};
    for (int k0 = 0; k0 < 256; k0 += 32) {
        sh8 a[4], w[4];
        for (int rt = 0; rt < 4; rt++) {
            size_t base = ((size_t)(b * GN) + row0 + rt * 16 + lrw) * GFI + k0 + quad * 8;
            if (isf) {
                const float* xp = (const float*)Xraw + base;
                f32x4g xa = *(const f32x4g*)xp;
                f32x4g xb = *(const f32x4g*)(xp + 4);
                sh8 t;
                for (int e = 0; e < 4; e++) {
                    t[e]     = (short)gat_f2bf(xa[e]);
                    t[e + 4] = (short)gat_f2bf(xb[e]);
                }
                a[rt] = t;
            } else {
                a[rt] = *(const sh8*)((const unsigned short*)Xraw + base);
            }
        }
        for (int ct = 0; ct < 4; ct++)
            w[ct] = *(const sh8*)&Wt[(ct * 16 + lrw) * LDW + k0 + quad * 8];
        for (int rt = 0; rt < 4; rt++)
            for (int ct = 0; ct < 4; ct++)
                acc[rt][ct] = __builtin_amdgcn_mfma_f32_16x16x32_bf16(a[rt], w[ct], acc[rt][ct], 0, 0, 0);
    }
    for (int rt = 0; rt < 4; rt++)
        for (int ct = 0; ct < 4; ct++) {
            int col = ct * 16 + lrw;
            int row = row0 + rt * 16 + quad * 4;
            us4g v;
            v[0] = gat_f2bf(acc[rt][ct][0]);
            v[1] = gat_f2bf(acc[rt][ct][1]);
            v[2] = gat_f2bf(acc[rt][ct][2]);
            v[3] = gat_f2bf(acc[rt][ct][3]);
            *(us4g*)&h_t[((size_t)(bh * 64 + col)) * GN + row] = v;
        }
#else
    int row = it * 256 + threadIdx.x;
    for (int col = 0; col < 64; col++) {
        float s = 0.f;
        for (int k = 0; k < 256; k++) {
            float xv = isf ? ((const float*)Xraw)[((size_t)(b * GN) + row) * GFI + k]
                           : gat_bf2f(((const unsigned short*)Xraw)[((size_t)(b * GN) + row) * GFI + k]);
            s += gat_bf2f(gat_f2bf(xv)) * gat_bf2f(Wt[col * LDW + k]);
        }
        h_t[((size_t)(bh * 64 + col)) * GN + row] = gat_f2bf(s);
    }
#endif
}

// --------------------------------------------------------------------------
// k_att: att_s/att_n (plain fp32) + per-bh max(att_n) via encoded atomicMax.
// grid 256 x 256 = 65536 threads; wave-uniform bh per wave.
// --------------------------------------------------------------------------
__global__ __launch_bounds__(256) void k_att(const unsigned short* __restrict__ h_t,
                                             const void* __restrict__ aSraw,
                                             const void* __restrict__ aNraw,
                                             const float* __restrict__ Aw,
                                             float* __restrict__ att_s,
                                             float* __restrict__ att_n,
                                             unsigned int* __restrict__ maxn_enc) {
    int idx = blockIdx.x * 256 + threadIdx.x;
    int bh = idx >> 11, n = idx & 2047;
    int hh = bh & 7;
    int isf = gat_isf32(Aw);
    float ss = 0.f, sn = 0.f;
    for (int o = 0; o < 64; o++) {
        float hv = gat_bf2f(h_t[((size_t)(bh * 64 + o)) * GN + n]);
        float as = isf ? ((const float*)aSraw)[hh * 64 + o]
                       : gat_bf2f(((const unsigned short*)aSraw)[hh * 64 + o]);
        float an = isf ? ((const float*)aNraw)[hh * 64 + o]
                       : gat_bf2f(((const unsigned short*)aNraw)[hh * 64 + o]);
        ss += hv * as;
        sn += hv * an;
    }
    att_s[idx] = ss;
    att_n[idx] = sn;
    // wave-reduce max(sn); one atomic per wave (bh is wave-uniform)
    float mx = sn;
    for (int off = 32; off; off >>= 1) mx = fmaxf(mx, __shfl_xor(mx, off, 64));
    if ((threadIdx.x & 63) == 0) atomicMax(&maxn_enc[bh], gat_enc(mx));
}

// --------------------------------------------------------------------------
// k_attn_av: out = relu( softmax(P) @ h ), P = exp(leaky(s_i+n_j) - c_i)*mask
// with c_i = leaky(s_i + maxn_bh) >= true row max (leaky monotone; softmax
// shift-invariant). l from ones-MFMA (row sums land in matching acc slots).
// grid 1024 (bh = blk&31, it = blk>>5), 128 thr = 2 waves x 32 rows.
// No LDS, no barriers, no cross-lane ops in the hot loop.
// --------------------------------------------------------------------------
__global__ __launch_bounds__(128, 2) void k_attn_av(const unsigned int* __restrict__ mask32,
                                                    const unsigned short* __restrict__ h_t,
                                                    const float* __restrict__ att_s,
                                                    const float* __restrict__ att_n,
                                                    const unsigned int* __restrict__ maxn_enc,
                                                    const float* __restrict__ Aw,
                                                    void* __restrict__ outv) {
    int blk = blockIdx.x;
    int bh = blk & 31, it = blk >> 5;
    int b = bh >> 3, hh = bh & 7;
    int i0 = it * 64;
    int tid = threadIdx.x;
    int isf = gat_isf32(Aw);
    float maxn = gat_dec(maxn_enc[bh]);
    const float* nrow = att_n + (size_t)bh * GN;
    const unsigned short* hb = h_t + (size_t)bh * 64 * GN;
#if defined(__gfx950__)
    int wave = tid >> 6, lane = tid & 63, lrw = lane & 15, quad = lane >> 4;
    int kq = quad * 8;
    int row0 = i0 + wave * 32 + lrw;
    int row1 = row0 + 16;
    float s0 = att_s[bh * GN + row0];
    float s1 = att_s[bh * GN + row1];
    float z0 = s0 + maxn, z1 = s1 + maxn;
    float c0 = fmaxf(z0, 0.2f * z0);       // upper bound on row max
    float c1 = fmaxf(z1, 0.2f * z1);
    const unsigned int* mr0 = mask32 + ((size_t)(b * GN) + row0) * 64;
    const unsigned int* mr1 = mask32 + ((size_t)(b * GN) + row1) * 64;
    f32x4g acc0[4] = {}, acc1[4] = {};
    f32x4g accl0 = {}, accl1 = {};
    sh8 ones;
#pragma unroll
    for (int e = 0; e < 8; e++) ones[e] = (short)0x3f80;  // bf16 1.0

    for (int jc = 0; jc < 64; jc++) {
        int jq = jc * 32 + kq;
        f32x4g nA = *(const f32x4g*)&nrow[jq];
        f32x4g nB = *(const f32x4g*)&nrow[jq + 4];
        unsigned int w0 = mr0[jc] >> kq;
        unsigned int w1 = mr1[jc] >> kq;
        float p0[8], p1[8];
#pragma unroll
        for (int e = 0; e < 8; e++) {
            float nv = (e < 4) ? nA[e] : nB[e - 4];
            float t0 = s0 + nv;
            float t1 = s1 + nv;
            float a0 = fmaxf(t0, 0.2f * t0) - c0;
            float a1 = fmaxf(t1, 0.2f * t1) - c1;
            a0 = ((w0 >> e) & 1u) ? a0 : -3e38f;   // exp -> exact 0
            a1 = ((w1 >> e) & 1u) ? a1 : -3e38f;
            p0[e] = __expf(a0);
            p1[e] = __expf(a1);
        }
        // truncation pack (bias cancels: l is computed from the packed P)
        i32x4g f0, f1;
#pragma unroll
        for (int pp = 0; pp < 4; pp++) {
            unsigned int u0 = __float_as_uint(p0[2 * pp]);
            unsigned int v0 = __float_as_uint(p0[2 * pp + 1]);
            unsigned int u1 = __float_as_uint(p1[2 * pp]);
            unsigned int v1 = __float_as_uint(p1[2 * pp + 1]);
            f0[pp] = (int)((u0 >> 16) | (v0 & 0xffff0000u));
            f1[pp] = (int)((u1 >> 16) | (v1 & 0xffff0000u));
        }
        sh8 af0 = *(sh8*)&f0;
        sh8 af1 = *(sh8*)&f1;
#pragma unroll
        for (int ct = 0; ct < 4; ct++) {
            sh8 bf = *(const sh8*)&hb[((size_t)(ct * 16 + lrw)) * GN + jq];
            acc0[ct] = __builtin_amdgcn_mfma_f32_16x16x32_bf16(af0, bf, acc0[ct], 0, 0, 0);
            acc1[ct] = __builtin_amdgcn_mfma_f32_16x16x32_bf16(af1, bf, acc1[ct], 0, 0, 0);
        }
        accl0 = __builtin_amdgcn_mfma_f32_16x16x32_bf16(af0, ones, accl0, 0, 0, 0);
        accl1 = __builtin_amdgcn_mfma_f32_16x16x32_bf16(af1, ones, accl1, 0, 0, 0);
    }
#pragma unroll
    for (int r = 0; r < 4; r++) {
        float li0 = 1.0f / accl0[r];       // l for row quad*4+r, same lane
        float li1 = 1.0f / accl1[r];
        int ra0 = i0 + wave * 32 + quad * 4 + r;
        int ra1 = ra0 + 16;
#pragma unroll
        for (int ct = 0; ct < 4; ct++) {
            int col = hh * 64 + ct * 16 + lrw;
            float v0 = acc0[ct][r] * li0; v0 = v0 > 0.f ? v0 : 0.f;
            float v1 = acc1[ct][r] * li1; v1 = v1 > 0.f ? v1 : 0.f;
            size_t o0 = ((size_t)(b * GN) + ra0) * GHF + col;
            size_t o1 = ((size_t)(b * GN) + ra1) * GHF + col;
            if (isf) { ((float*)outv)[o0] = v0; ((float*)outv)[o1] = v1; }
            else     { ((unsigned short*)outv)[o0] = gat_f2bf(v0);
                       ((unsigned short*)outv)[o1] = gat_f2bf(v1); }
        }
    }
#else
    // correctness-only fallback: thread -> (row, 32-col half)
    int row = i0 + (tid >> 1), chh = (tid & 1) * 32;
    const unsigned int* mr = mask32 + ((size_t)(b * GN) + row) * 64;
    float s = att_s[bh * GN + row];
    float z = s + maxn;
    float c = fmaxf(z, 0.2f * z);
    float l = 0.f;
    float accS[32] = {};
    for (int j = 0; j < GN; j++) {
        if (!((mr[j >> 5] >> (j & 31)) & 1u)) continue;
        float x = s + nrow[j]; x = fmaxf(x, 0.2f * x);
        float p = __expf(x - c);
        union { float f; unsigned int u; } t; t.f = p; t.u &= 0xffff0000u;  // trunc
        l += t.f;
        for (int cc = 0; cc < 32; cc++)
            accS[cc] += t.f * gat_bf2f(hb[(size_t)(chh + cc) * GN + j]);
    }
    float li = 1.0f / l;
    for (int cc = 0; cc < 32; cc++) {
        float v = accS[cc] * li; v = v > 0.f ? v : 0.f;
        size_t oi = ((size_t)(b * GN) + row) * GHF + hh * 64 + chh + cc;
        if (isf) ((float*)outv)[oi] = v;
        else     ((unsigned short*)outv)[oi] = gat_f2bf(v);
    }
#endif
}

// --------------------------------------------------------------------------
extern "C" void kernel_launch(void* const* d_in, const int* in_sizes, int n_in,
                              void* d_out, int out_size, void* d_ws, size_t ws_size,
                              hipStream_t stream) {
    const void* X  = d_in[0];
    const void* A  = d_in[1];
    const void* W  = d_in[2];
    const void* aS = d_in[3];
    const void* aN = d_in[4];

    char* ws = (char*)d_ws;
    constexpr size_t OFF_HT   = 256;
    constexpr size_t OFF_ATTS = OFF_HT + (size_t)32 * 64 * 2048 * 2;  // 8 MB
    constexpr size_t OFF_ATTN = OFF_ATTS + 262144;
    constexpr size_t OFF_MASK = OFF_ATTN + 262144;                    // 2 MB
    constexpr size_t OFF_MAXN = OFF_MASK + (size_t)2097152;

    unsigned short* h_t = (unsigned short*)(ws + OFF_HT);
    float* att_s = (float*)(ws + OFF_ATTS);
    float* att_n = (float*)(ws + OFF_ATTN);
    unsigned long long* mask = (unsigned long long*)(ws + OFF_MASK);
    unsigned int* maxn_enc = (unsigned int*)(ws + OFF_MAXN);

    k_mask<<<65536, 256, 0, stream>>>(A, mask, maxn_enc);
    k_gemm1<<<256, 256, 0, stream>>>(X, W, (const float*)A, h_t);
    k_att<<<256, 256, 0, stream>>>(h_t, aS, aN, (const float*)A,
                                   att_s, att_n, maxn_enc);
    k_attn_av<<<1024, 128, 0, stream>>>((const unsigned int*)mask, h_t,
                                        att_s, att_n, maxn_enc,
                                        (const float*)A, d_out);
}